// Round 11
// baseline (159.031 us; speedup 1.0000x reference)
//
#include <hip/hip_runtime.h>

// Problem constants (fixed in the reference file)
#define OHh   60
#define OWw   60
#define NBINS (OHh * OWw)   // 3600
#define NB    64            // batches
#define NS    4096          // spikes per batch
#define CAP   128

#define NW     4            // waves per block
#define SEG    (NS / NW)    // 1024 spikes scanned per wave
#define CH     (SEG / 64)   // 16 chunks per wave
#define WSLOTS 40           // staged slots per wave-segment per bin (+1 dummy row)
#define PRE0   64           // slots [PRE0, CAP) prefilled -1 during scan
                            // (per-bin total ~ Poisson(25); P(>64) ~ 1e-11)

// One 4-wave block per (batch, output row); lane == ow (lanes 60..63 parked).
// R10 post-mortem: prefill depth neutral -> critical path is the scan's LDS
// pipe work (~11 DS wave-instrs/chunk ~= 26 us/CU). R11 cuts it ~2.3x:
//  - ds_read_b64 pulls 4 hit payloads per instr (vs 4x ds_read_u16);
//  - hits in a 4-group mostly cover DISJOINT lanes (windows overlap only if
//    |dw|<5), so one shared ds_write_b16 round stores one match per lane;
//    lanes matching >=2 hits loop extra rounds (E ~ 0.25/group). Per-lane
//    ctz low->high == hit order == s order, so FCFS rank is exact.
// Everything else frozen: row-per-block, batch-minor swizzle, [64,128) -1
// prefill hidden under the scan, contiguous-240B dump (WRITE_SIZE ~= 1.0x).
__global__ __launch_bounds__(256) void sort_spikes_row4(
    const int* __restrict__ spikes, int* __restrict__ out) {
    const int bid  = (int)blockIdx.x;
    const int b    = bid & (NB - 1);   // batch-minor -> batch b pinned to XCD b%8
    const int row  = bid >> 6;         // output row oh, 0..59
    const int tid  = (int)threadIdx.x;
    const int wv   = tid >> 6;
    const int lane = tid & 63;
    const bool valid  = lane < OWw;
    const int  lane_c = valid ? lane : 127;  // parked lanes: window test auto-fails

    __shared__ short          stage[NW][WSLOTS + 1][64];  // 20992 B (+1 dummy sink)
    __shared__ unsigned short hits[NW][64];               // compacted chunk payloads
    __shared__ int            cnt[NW][64];
    __shared__ int            ovf;

    if (tid == 0) ovf = 0;

    const int* __restrict__ sp   = spikes + b * NS + wv * SEG;
    int* __restrict__       outb = out + (size_t)b * (CAP * NBINS) + row * OWw;

    // Issue all 16 chunk loads up front (deep vmcnt pipeline; L2-resident
    // after the first of a batch's 60 blocks touches them).
    int vs[CH];
#pragma unroll
    for (int c = 0; c < CH; ++c) vs[c] = sp[c * 64 + lane];

    unsigned short* const hitbuf      = &hits[wv][0];
    short* const          stage_lane  = &stage[wv][0][lane];      // + count*64 shorts
    short* const          stage_dummy = &stage[wv][WSLOTS][lane]; // sink row

    int count = 0;
#pragma unroll
    for (int c = 0; c < CH; ++c) {
        const int v   = vs[c];
        const int kh  = ((v >> 6) & 63) - row;
        const bool halo = (unsigned)kh < 5u;
        const int w   = v & 63;
        const int A   = (v >> 12) * 25 + kh * 5 + w;  // ckk_base + w, fits 10 bits
        const unsigned short P = (unsigned short)((w << 10) | A);

        const unsigned long long mask = __ballot(halo);   // wave-uniform
        const int pos = __builtin_amdgcn_mbcnt_hi(
            (unsigned)(mask >> 32),
            __builtin_amdgcn_mbcnt_lo((unsigned)mask, 0));  // rank among halo lanes
        if (halo) hitbuf[pos] = P;                          // s-order preserved
        const int n = __popcll(mask);                       // uniform

        for (int i = 0; i < n; i += 4) {          // uniform trip count
            // One ds_read_b64: payloads for hits i..i+3 (8B-aligned; entries
            // past n are stale garbage, masked out below by i+k<n).
            const ushort4 q = *(const ushort4*)(hitbuf + i);
            const int p0 = q.x, p1 = q.y, p2 = q.z, p3 = q.w;

            // Per-lane 4-bit match mask (bit k == hit i+k covers this lane).
            int mm = 0;
            if (((unsigned)((p0 >> 10) - lane_c) < 5u) & (i + 0 < n)) mm |= 1;
            if (((unsigned)((p1 >> 10) - lane_c) < 5u) & (i + 1 < n)) mm |= 2;
            if (((unsigned)((p2 >> 10) - lane_c) < 5u) & (i + 2 < n)) mm |= 4;
            if (((unsigned)((p3 >> 10) - lane_c) < 5u) & (i + 3 < n)) mm |= 8;

            // Write rounds: usually 1 (disjoint windows); lanes with >=2
            // matches keep looping (exec-masked). ctz order == s order.
            while (mm) {
                const int t  = __builtin_ctz(mm);
                mm &= mm - 1;
                const int pa = (t & 1) ? p1 : p0;
                const int pb = (t & 1) ? p3 : p2;
                const int pt = (t & 2) ? pb : pa;
                short* a = (count < WSLOTS) ? (stage_lane + count * 64)
                                            : stage_dummy;
                *a = (short)((pt & 0x3ff) - lane_c);   // == ckk for this lane
                ++count;
            }
        }

        // Hidden write: one -1 slot-row per chunk -> slots [64,128) done by
        // scan end. Contiguous 240 B run, paced under the scan.
        if (valid) outb[(PRE0 + wv * CH + c) * NBINS + lane] = -1;
    }
    cnt[wv][lane] = count;
    if (__ballot(count > WSLOTS) && lane == 0) ovf = 1;  // benign multi-write
    __syncthreads();

    if (ovf == 0) {
        if (valid) {
            const int c0 = cnt[0][lane], c1 = cnt[1][lane];
            const int c2 = cnt[2][lane], c3 = cnt[3][lane];
            const int o1 = c0, o2 = c0 + c1, o3 = o2 + c2;
            const int total = o3 + c3;                 // <=160
            // Dump slots [0,64): 16 per wave, wave order == s order.
#pragma unroll 4
            for (int i = 0; i < PRE0 / NW; ++i) {
                const int k = wv * (PRE0 / NW) + i;
                int val = -1;
                if (k < total) {
                    int wsel = 0, base = 0;
                    if (k >= o1) { wsel = 1; base = o1; }
                    if (k >= o2) { wsel = 2; base = o2; }
                    if (k >= o3) { wsel = 3; base = o3; }
                    val = (int)stage[wsel][k - base][lane];  // bank=lane>>1, free
                }
                outb[k * NBINS + lane] = val;          // contiguous 240 B run
            }
            // Astronomically rare (P(total>64) ~ 1e-11): overwrite prefilled
            // -1s with real staged values.
            for (int k = PRE0 + wv; k < total && k < CAP; k += NW) {
                int wsel = 0, base = 0;
                if (k >= o1) { wsel = 1; base = o1; }
                if (k >= o2) { wsel = 2; base = o2; }
                if (k >= o3) { wsel = 3; base = o3; }
                outb[k * NBINS + lane] = (int)stage[wsel][k - base][lane];
            }
        }
    } else if (wv == 0) {
        // Fallback: >40 staged hits in one bin from one 1024-spike segment
        // (P ~ 1e-22 random input). Serial redo, direct global stores.
        const int* __restrict__ spf = spikes + b * NS;
        int cc = 0;
        for (int c = 0; c < NS / 64; ++c) {
            const int v = spf[c * 64 + lane];
            const int h = (v >> 6) & 63;
            unsigned long long mask = __ballot((unsigned)(h - row) < 5u);
            while (mask) {
                const int j = (int)__builtin_ctzll(mask);
                mask &= mask - 1;
                const int vj =
                    __builtin_amdgcn_readlane(v, __builtin_amdgcn_readfirstlane(j));
                const int wj  = vj & 63;
                const int khj = ((vj >> 6) & 63) - row;
                const int cj  = vj >> 12;
                const int kw  = wj - lane_c;
                if ((unsigned)kw < 5u) {
                    if (cc < CAP)
                        outb[cc * NBINS + lane] = cj * 25 + khj * 5 + kw;
                    ++cc;
                }
            }
        }
        if (valid)
            for (int k = cc; k < CAP; ++k) outb[k * NBINS + lane] = -1;
    }
}

extern "C" void kernel_launch(void* const* d_in, const int* in_sizes, int n_in,
                              void* d_out, int out_size, void* d_ws, size_t ws_size,
                              hipStream_t stream) {
    const int* spikes = (const int*)d_in[0];  // (B, S, 1, 1) int32
    // d_in[1] (indices table) unused: membership is pure arithmetic.
    int* out = (int*)d_out;                   // (B, CAP, OH, OW) int32

    dim3 grid(OHh * NB);                      // 3840 blocks, batch-minor
    dim3 block(256);                          // 4 waves/block
    sort_spikes_row4<<<grid, block, 0, stream>>>(spikes, out);
}

// Round 12
// 152.740 us; speedup vs baseline: 1.0412x; 1.0412x over previous
//
#include <hip/hip_runtime.h>

// Problem constants (fixed in the reference file)
#define OHh   60
#define OWw   60
#define NBINS (OHh * OWw)   // 3600
#define NB    64            // batches
#define NS    4096          // spikes per batch
#define CAP   128

#define NW     4            // waves per block
#define SEG    (NS / NW)    // 1024 spikes scanned per wave
#define CH     (SEG / 64)   // 16 chunks per wave
#define WSLOTS 40           // staged slots per wave-segment per bin (+1 dummy row)
#define PRE0   64           // slots [PRE0, CAP) prefilled -1 during scan
                            // (per-bin total ~ Poisson(25); P(>64) ~ 1e-11)

// One 4-wave block per (batch, output row); lane == ow (lanes 60..63 parked).
// R11 post-mortem: divergent per-lane match-mask loop regressed. R12 keeps
// R8's flat structure but processes hits TWO per round, all non-divergent:
//  - one ds_read_b32 fetches both payloads (halves hit reads);
//  - one predicated ds_write_b16 stores the EARLIER matching hit per lane
//    (s-order exact); lanes matching both hits (P~0.6%) get a second write
//    round guarded by uniform __any(both) (~1/3 of rounds taken);
//  - count += m0+m1 keeps per-lane counts exact.
// DS/chunk ~11 -> ~7. Everything else frozen from R8: row-per-block,
// batch-minor swizzle, [64,128) -1 prefill hidden under the scan,
// contiguous-240B dump (WRITE_SIZE ~= 1.0x output).
__global__ __launch_bounds__(256) void sort_spikes_row4(
    const int* __restrict__ spikes, int* __restrict__ out) {
    const int bid  = (int)blockIdx.x;
    const int b    = bid & (NB - 1);   // batch-minor -> batch b pinned to XCD b%8
    const int row  = bid >> 6;         // output row oh, 0..59
    const int tid  = (int)threadIdx.x;
    const int wv   = tid >> 6;
    const int lane = tid & 63;
    const bool valid  = lane < OWw;
    const int  lane_c = valid ? lane : 127;  // parked lanes: window test auto-fails

    __shared__ short          stage[NW][WSLOTS + 1][64];  // 20992 B (+1 dummy sink)
    __shared__ unsigned short hits[NW][64];               // compacted chunk payloads
    __shared__ int            cnt[NW][64];
    __shared__ int            ovf;

    if (tid == 0) ovf = 0;

    const int* __restrict__ sp   = spikes + b * NS + wv * SEG;
    int* __restrict__       outb = out + (size_t)b * (CAP * NBINS) + row * OWw;

    // Issue all 16 chunk loads up front (deep vmcnt pipeline; L2-resident
    // after the first of a batch's 60 blocks touches them).
    int vs[CH];
#pragma unroll
    for (int c = 0; c < CH; ++c) vs[c] = sp[c * 64 + lane];

    unsigned short* const  hitbuf      = &hits[wv][0];
    const unsigned* const  hitbuf32    = (const unsigned*)&hits[wv][0];
    short* const           stage_lane  = &stage[wv][0][lane];      // + count*64 shorts
    short* const           stage_dummy = &stage[wv][WSLOTS][lane]; // sink row

    int count = 0;
#pragma unroll
    for (int c = 0; c < CH; ++c) {
        const int v   = vs[c];
        const int kh  = ((v >> 6) & 63) - row;
        const bool halo = (unsigned)kh < 5u;
        const int w   = v & 63;
        const int A   = (v >> 12) * 25 + kh * 5 + w;  // ckk_base + w, fits 10 bits
        const unsigned short P = (unsigned short)((w << 10) | A);

        const unsigned long long mask = __ballot(halo);   // wave-uniform
        const int pos = __builtin_amdgcn_mbcnt_hi(
            (unsigned)(mask >> 32),
            __builtin_amdgcn_mbcnt_lo((unsigned)mask, 0));  // rank among halo lanes
        if (halo) hitbuf[pos] = P;                          // s-order preserved
        const int n = __popcll(mask);                       // uniform

        for (int i = 0; i < n; i += 2) {          // uniform trip count
            // One ds_read_b32 (same-addr broadcast): hits i and i+1.
            const unsigned q  = hitbuf32[i >> 1];
            const int P0 = (int)(q & 0xffffu);
            const int P1 = (int)(q >> 16);        // stale garbage if i+1>=n
            const bool hi_ok = (i + 1 < n);       // uniform

            const bool m0 = (unsigned)((P0 >> 10) - lane_c) < 5u;
            const bool m1 = ((unsigned)((P1 >> 10) - lane_c) < 5u) & hi_ok;
            const int  v0 = (P0 & 0x3ff) - lane_c;   // == ckk when m0
            const int  v1 = (P1 & 0x3ff) - lane_c;   // == ckk when m1

            // First write: earlier matching hit (s-order).
            const bool any1 = m0 | m1;
            short* a = (any1 & (count < WSLOTS)) ? (stage_lane + count * 64)
                                                 : stage_dummy;
            *a = (short)(m0 ? v0 : v1);

            // Second write only if some lane matches BOTH (uniform branch,
            // taken ~1/3 of rounds; that lane stores v1 at count+1).
            const bool both = m0 & m1;
            if (__any(both)) {
                const int c2 = count + 1;
                short* a2 = (both & (c2 < WSLOTS)) ? (stage_lane + c2 * 64)
                                                   : stage_dummy;
                *a2 = (short)v1;
            }
            count += (int)m0 + (int)m1;
        }

        // Hidden write: one -1 slot-row per chunk -> slots [64,128) done by
        // scan end. Contiguous 240 B run, paced under the scan.
        if (valid) outb[(PRE0 + wv * CH + c) * NBINS + lane] = -1;
    }
    cnt[wv][lane] = count;
    if (__ballot(count > WSLOTS) && lane == 0) ovf = 1;  // benign multi-write
    __syncthreads();

    if (ovf == 0) {
        if (valid) {
            const int c0 = cnt[0][lane], c1 = cnt[1][lane];
            const int c2 = cnt[2][lane], c3 = cnt[3][lane];
            const int o1 = c0, o2 = c0 + c1, o3 = o2 + c2;
            const int total = o3 + c3;                 // <=160
            // Dump slots [0,64): 16 per wave, wave order == s order.
#pragma unroll 4
            for (int i = 0; i < PRE0 / NW; ++i) {
                const int k = wv * (PRE0 / NW) + i;
                int val = -1;
                if (k < total) {
                    int wsel = 0, base = 0;
                    if (k >= o1) { wsel = 1; base = o1; }
                    if (k >= o2) { wsel = 2; base = o2; }
                    if (k >= o3) { wsel = 3; base = o3; }
                    val = (int)stage[wsel][k - base][lane];  // bank=lane>>1, free
                }
                outb[k * NBINS + lane] = val;          // contiguous 240 B run
            }
            // Astronomically rare (P(total>64) ~ 1e-11): overwrite prefilled
            // -1s with real staged values.
            for (int k = PRE0 + wv; k < total && k < CAP; k += NW) {
                int wsel = 0, base = 0;
                if (k >= o1) { wsel = 1; base = o1; }
                if (k >= o2) { wsel = 2; base = o2; }
                if (k >= o3) { wsel = 3; base = o3; }
                outb[k * NBINS + lane] = (int)stage[wsel][k - base][lane];
            }
        }
    } else if (wv == 0) {
        // Fallback: >40 staged hits in one bin from one 1024-spike segment
        // (P ~ 1e-22 random input). Serial redo, direct global stores.
        const int* __restrict__ spf = spikes + b * NS;
        int cc = 0;
        for (int c = 0; c < NS / 64; ++c) {
            const int v = spf[c * 64 + lane];
            const int h = (v >> 6) & 63;
            unsigned long long mask = __ballot((unsigned)(h - row) < 5u);
            while (mask) {
                const int j = (int)__builtin_ctzll(mask);
                mask &= mask - 1;
                const int vj =
                    __builtin_amdgcn_readlane(v, __builtin_amdgcn_readfirstlane(j));
                const int wj  = vj & 63;
                const int khj = ((vj >> 6) & 63) - row;
                const int cj  = vj >> 12;
                const int kw  = wj - lane_c;
                if ((unsigned)kw < 5u) {
                    if (cc < CAP)
                        outb[cc * NBINS + lane] = cj * 25 + khj * 5 + kw;
                    ++cc;
                }
            }
        }
        if (valid)
            for (int k = cc; k < CAP; ++k) outb[k * NBINS + lane] = -1;
    }
}

extern "C" void kernel_launch(void* const* d_in, const int* in_sizes, int n_in,
                              void* d_out, int out_size, void* d_ws, size_t ws_size,
                              hipStream_t stream) {
    const int* spikes = (const int*)d_in[0];  // (B, S, 1, 1) int32
    // d_in[1] (indices table) unused: membership is pure arithmetic.
    int* out = (int*)d_out;                   // (B, CAP, OH, OW) int32

    dim3 grid(OHh * NB);                      // 3840 blocks, batch-minor
    dim3 block(256);                          // 4 waves/block
    sort_spikes_row4<<<grid, block, 0, stream>>>(spikes, out);
}